// Round 13
// baseline (209.108 us; speedup 1.0000x reference)
//
#include <hip/hip_runtime.h>
#include <hip/hip_bf16.h>
#include <math.h>

#define Bq 512
#define Cq 80
#define Fq 768
#define Hq 256

constexpr float EPS   = 1e-5f;
constexpr float THR   = 0.5f;
constexpr float SCALE = 0.0625f;   // 1/sqrt(256)

using f32x4 = __attribute__((ext_vector_type(4))) float;
using s16x8 = __attribute__((ext_vector_type(8))) short;
using s16x4 = __attribute__((ext_vector_type(4))) short;

#define MFMA16 __builtin_amdgcn_mfma_f32_16x16x32_bf16

// Fragment-packed layout (A rows=M / B rows=N), addr in elements:
//   ((tile*8 + kk8)*4 + g)*128 + l15*8 + e
// tile = row/16, l15 = row%16, kk8 = k/32, g = (k%32)/8, e = k%8.

__device__ __forceinline__ float waveReduceSum(float v) {
#pragma unroll
  for (int m = 32; m >= 1; m >>= 1) v += __shfl_xor(v, m);
  return v;
}

__device__ __forceinline__ float bfu(unsigned short v) {
  return __uint_as_float(((unsigned)v) << 16);
}

__device__ __forceinline__ unsigned short f2bf(float f) {
  __hip_bfloat16 h = __float2bfloat16(f);   // RNE
  return *reinterpret_cast<unsigned short*>(&h);
}

__device__ __forceinline__ int packOff(int tile, int kk8, int g, int l15, int e) {
  return ((tile * 8 + kk8) * 4 + g) * 128 + l15 * 8 + e;
}

// ---------------------------------------------------------------------------
// K_setup (merged): blocks 0..511 visproj | 512..767 matmulM | 768..1791 prep
// ---------------------------------------------------------------------------
__global__ __launch_bounds__(256) void k_setup(
    const float* __restrict__ vf, const float* __restrict__ Wp,
    const float* __restrict__ bp, const float* __restrict__ gp,
    const float* __restrict__ bep,
    unsigned short* __restrict__ visPh, unsigned short* __restrict__ visPl,
    const float* __restrict__ Wq, const float* __restrict__ Wk,
    const float* __restrict__ bq, const float* __restrict__ bk,
    unsigned short* __restrict__ MTph, unsigned short* __restrict__ MTpl,
    float* __restrict__ w1, float* __restrict__ w2, float* __restrict__ cqk,
    const float* __restrict__ Wc, const float* __restrict__ Wv,
    const float* __restrict__ Wo,
    unsigned short* __restrict__ WcTph, unsigned short* __restrict__ WcTpl,
    unsigned short* __restrict__ WvTp, unsigned short* __restrict__ WoTp) {
  __shared__ float smA[Fq];
  __shared__ float red[4], redB[4], redC[4];
  const int blk = blockIdx.x;

  if (blk < 512) {
    // ---- visproj: vis = relu(LN(vf @ Wp + bp)) -> packed-A hi/lo ----
    const int b = blk, h = threadIdx.x;
    for (int i = h; i < Fq; i += 256) smA[i] = vf[b * Fq + i];
    __syncthreads();
    float acc = bp[h];
    for (int f = 0; f < Fq; f++) acc = fmaf(smA[f], Wp[f * Hq + h], acc);
    const int w = h >> 6, lane = h & 63;
    float s = waveReduceSum(acc);
    if (lane == 0) red[w] = s;
    __syncthreads();
    const float mean = (red[0] + red[1] + red[2] + red[3]) * (1.0f / Hq);
    __syncthreads();
    const float d = acc - mean;
    s = waveReduceSum(d * d);
    if (lane == 0) red[w] = s;
    __syncthreads();
    const float var = (red[0] + red[1] + red[2] + red[3]) * (1.0f / Hq);
    float y = d * rsqrtf(var + EPS) * gp[h] + bep[h];
    y = fmaxf(y, 0.0f);
    const unsigned short hb = f2bf(y);
    const int off = packOff(b >> 4, h >> 5, (h & 31) >> 3, b & 15, h & 7);
    visPh[off] = hb;
    visPl[off] = f2bf(y - bfu(hb));
  } else if (blk < 768) {
    // ---- matmulM: M = Wq@Wk^T -> packed-B hi/lo; w1,w2,cqk ----
    const int i = blk - 512, j = threadIdx.x;
    const int wv = j >> 6, lane = j & 63;
    smA[j] = Wq[i * Hq + j];
    __syncthreads();
    float acc = 0.f;
    const float* wkr = Wk + (size_t)j * Hq;
    for (int h = 0; h < Hq; h += 4) {
      const float4 a = *reinterpret_cast<const float4*>(&smA[h]);
      const float4 bb = *reinterpret_cast<const float4*>(&wkr[h]);
      acc = fmaf(a.x, bb.x, fmaf(a.y, bb.y, fmaf(a.z, bb.z, fmaf(a.w, bb.w, acc))));
    }
    const unsigned short hb = f2bf(acc);
    const int off = packOff(j >> 4, i >> 5, (i & 31) >> 3, j & 15, i & 7);
    MTph[off] = hb;
    MTpl[off] = f2bf(acc - bfu(hb));
    float p1 = smA[j] * bk[j];
    float p2 = Wk[(size_t)i * Hq + j] * bq[j];
    float p3 = bq[j] * bk[j];
    p1 = waveReduceSum(p1);
    p2 = waveReduceSum(p2);
    p3 = waveReduceSum(p3);
    if (lane == 0) { red[wv] = p1; redB[wv] = p2; redC[wv] = p3; }
    __syncthreads();
    if (j == 0) {
      w1[i] = red[0] + red[1] + red[2] + red[3];
      w2[i] = redB[0] + redB[1] + redB[2] + redB[3];
      if (i == 0) *cqk = redC[0] + redC[1] + redC[2] + redC[3];
    }
  } else {
    // ---- prep: pack Wc (hi/lo), Wv (hi), Wo (hi) into B-frag layout ----
    const int NWc = Cq * 32 * 256;
    const int NTOT = NWc + 2 * 32 * 256;
    for (int idx = (blk - 768) * 256 + threadIdx.x; idx < NTOT; idx += 1024 * 256) {
      if (idx < NWc) {
        const int c = idx >> 13, k8 = (idx >> 8) & 31, n = idx & 255;
        const float* src = Wc + (size_t)c * 65536 + (size_t)k8 * 8 * 256 + n;
        s16x8 hh, ll;
#pragma unroll
        for (int e = 0; e < 8; e++) {
          const float v = src[e * 256];
          const unsigned short hb = f2bf(v);
          hh[e] = (short)hb;
          ll[e] = (short)f2bf(v - bfu(hb));
        }
        const int off = c * 65536 + packOff(n >> 4, k8 >> 2, k8 & 3, n & 15, 0);
        *reinterpret_cast<s16x8*>(WcTph + off) = hh;
        *reinterpret_cast<s16x8*>(WcTpl + off) = ll;
      } else {
        const int r = idx - NWc;
        const int which = r >> 13;           // 0 = Wv, 1 = Wo
        const int r2 = r & 8191;
        const int k8 = r2 >> 8, n = r2 & 255;
        const float* src = (which == 0 ? Wv : Wo) + (size_t)k8 * 8 * 256 + n;
        s16x8 hh;
#pragma unroll
        for (int e = 0; e < 8; e++) hh[e] = (short)f2bf(src[e * 256]);
        const int off = packOff(n >> 4, k8 >> 2, k8 & 3, n & 15, 0);
        *reinterpret_cast<s16x8*>((which == 0 ? WvTp : WoTp) + off) = hh;
      }
    }
  }
}

// ---------------------------------------------------------------------------
// GEMM1: Z = vis@Wc[c]+bc (split-3 MFMA) -> LN -> relu -> +x -> X'
// (verbatim: the 194.2us-measured version)
// ---------------------------------------------------------------------------
__global__ __launch_bounds__(256) void k_gemm1f(
    const unsigned short* __restrict__ visPh, const unsigned short* __restrict__ visPl,
    const unsigned short* __restrict__ WcTph, const unsigned short* __restrict__ WcTpl,
    const float* __restrict__ x, const float* __restrict__ bc,
    const float* __restrict__ gc, const float* __restrict__ bec,
    const float* __restrict__ w1, const float* __restrict__ w2,
    unsigned short* __restrict__ Xgh, unsigned short* __restrict__ Xgl,
    float* __restrict__ u, float* __restrict__ vv) {
  const int blk = blockIdx.x;
  const int mapped = (blk & 7) * 160 + (blk >> 3);
  const int c = mapped >> 4;
  const int bx = mapped & 15;
  const int b0 = bx * 32;
  const int tid = threadIdx.x;
  const int wvi = tid >> 6, lane = tid & 63;
  const int l15 = lane & 15, l4 = lane >> 4;

  __shared__ float Zs[32][268];   // 268 pad: kills l4-lane same-bank conflicts

  f32x4 acc[2][4];
#pragma unroll
  for (int m = 0; m < 2; m++)
#pragma unroll
    for (int n = 0; n < 4; n++) acc[m][n] = (f32x4){0.f, 0.f, 0.f, 0.f};

  const unsigned short* Bh = WcTph + (size_t)c * 65536;
  const unsigned short* Bl = WcTpl + (size_t)c * 65536;

  for (int kk8 = 0; kk8 < 8; kk8++) {
    s16x8 ah[2], al[2], bh[4], bl[4];
#pragma unroll
    for (int m = 0; m < 2; m++) {
      const int off = packOff(bx * 2 + m, kk8, l4, l15, 0);
      ah[m] = *reinterpret_cast<const s16x8*>(visPh + off);
      al[m] = *reinterpret_cast<const s16x8*>(visPl + off);
    }
#pragma unroll
    for (int n = 0; n < 4; n++) {
      const int off = packOff(wvi * 4 + n, kk8, l4, l15, 0);
      bh[n] = *reinterpret_cast<const s16x8*>(Bh + off);
      bl[n] = *reinterpret_cast<const s16x8*>(Bl + off);
    }
#pragma unroll
    for (int m = 0; m < 2; m++)
#pragma unroll
      for (int n = 0; n < 4; n++) {
        acc[m][n] = MFMA16(ah[m], bh[n], acc[m][n], 0, 0, 0);
        acc[m][n] = MFMA16(ah[m], bl[n], acc[m][n], 0, 0, 0);
        acc[m][n] = MFMA16(al[m], bh[n], acc[m][n], 0, 0, 0);
      }
  }

#pragma unroll
  for (int m = 0; m < 2; m++)
#pragma unroll
    for (int n = 0; n < 4; n++) {
      const int col = wvi * 64 + n * 16 + l15;
      const float bcv = bc[c * Hq + col];
#pragma unroll
      for (int r = 0; r < 4; r++)
        Zs[m * 16 + l4 * 4 + r][col] = acc[m][n][r] + bcv;
    }
  __syncthreads();

  const int row = tid >> 3, sub = tid & 7;
  const int grow = b0 + row;
  const size_t xrow = ((size_t)grow * Cq + c) * Hq;
  float zz[32];
  float sum = 0.f, sumsq = 0.f;
#pragma unroll
  for (int kq = 0; kq < 8; kq++) {
    const float4 z = *reinterpret_cast<const float4*>(&Zs[row][sub * 4 + kq * 32]);
    zz[4 * kq + 0] = z.x; zz[4 * kq + 1] = z.y;
    zz[4 * kq + 2] = z.z; zz[4 * kq + 3] = z.w;
    sum += z.x + z.y + z.z + z.w;
    sumsq += z.x * z.x + z.y * z.y + z.z * z.z + z.w * z.w;
  }
#pragma unroll
  for (int msk = 4; msk >= 1; msk >>= 1) {
    sum += __shfl_xor(sum, msk);
    sumsq += __shfl_xor(sumsq, msk);
  }
  const float mean = sum * (1.0f / Hq);
  const float var = sumsq * (1.0f / Hq) - mean * mean;
  const float inv = rsqrtf(var + EPS);

  float pu = 0.f, pv = 0.f;
#pragma unroll
  for (int kq = 0; kq < 8; kq++) {
    const int col = sub * 4 + kq * 32;
    const float4 xv = *reinterpret_cast<const float4*>(&x[xrow + col]);
    const float xr[4] = {xv.x, xv.y, xv.z, xv.w};
    s16x4 hh, ll;
#pragma unroll
    for (int e = 0; e < 4; e++) {
      float tt = (zz[4 * kq + e] - mean) * inv * gc[c * Hq + col + e] + bec[c * Hq + col + e];
      tt = fmaxf(tt, 0.f);
      const float xp = xr[e] + tt;
      const unsigned short hb2 = f2bf(xp);
      hh[e] = (short)hb2;
      ll[e] = (short)f2bf(xp - bfu(hb2));
      pu = fmaf(xp, w1[col + e], pu);
      pv = fmaf(xp, w2[col + e], pv);
    }
    *reinterpret_cast<s16x4*>(Xgh + xrow + col) = hh;   // linear, coalesced
    *reinterpret_cast<s16x4*>(Xgl + xrow + col) = ll;
  }
#pragma unroll
  for (int msk = 4; msk >= 1; msk >>= 1) {
    pu += __shfl_xor(pu, msk);
    pv += __shfl_xor(pv, msk);
  }
  if (sub == 0) {
    u[(size_t)grow * Cq + c] = pu;
    vv[(size_t)grow * Cq + c] = pv;
  }
}

// ---------------------------------------------------------------------------
// GEMM2 (repack hub): (verbatim: the 194.2us-measured version)
// ---------------------------------------------------------------------------
__global__ __launch_bounds__(256) void k_gemm2p(
    unsigned short* Xh, unsigned short* Xl,       // aliased on purpose
    const unsigned short* __restrict__ MTph, const unsigned short* __restrict__ MTpl,
    const unsigned short* __restrict__ WvTp, const float* __restrict__ bv,
    unsigned short* __restrict__ XMh, unsigned short* __restrict__ XMl,
    unsigned short* __restrict__ Vt) {
  __shared__ __attribute__((aligned(16))) unsigned short Xsh[32 * 264];
  __shared__ __attribute__((aligned(16))) unsigned short Xsl[32 * 264];
  __shared__ __attribute__((aligned(16))) unsigned short XMsh[8192];
  __shared__ __attribute__((aligned(16))) unsigned short XMsl[8192];
  __shared__ __attribute__((aligned(16))) unsigned short Vst[256 * 24];

  const int blk = blockIdx.x;
  const int r0 = blk * 32;
  const int tid = threadIdx.x;
  const int wvi = tid >> 6, lane = tid & 63;
  const int l15 = lane & 15, l4 = lane >> 4;

#pragma unroll
  for (int it = 0; it < 4; it++) {
    const int ch = it * 256 + tid;
    const int rr = ch >> 5, cc = ch & 31;
    const size_t gsrc = (size_t)(r0 + rr) * Hq + cc * 8;
    *reinterpret_cast<s16x8*>(&Xsh[rr * 264 + cc * 8]) =
        *reinterpret_cast<const s16x8*>(Xh + gsrc);
    *reinterpret_cast<s16x8*>(&Xsl[rr * 264 + cc * 8]) =
        *reinterpret_cast<const s16x8*>(Xl + gsrc);
  }
  __syncthreads();

  f32x4 acc[2][4];
#pragma unroll
  for (int m = 0; m < 2; m++)
#pragma unroll
    for (int n = 0; n < 4; n++) acc[m][n] = (f32x4){0.f, 0.f, 0.f, 0.f};

  for (int kk8 = 0; kk8 < 8; kk8++) {
    s16x8 ah[2], al[2], bh[4], bl[4];
#pragma unroll
    for (int m = 0; m < 2; m++) {
      const int lo = (m * 16 + l15) * 264 + kk8 * 32 + l4 * 8;
      ah[m] = *reinterpret_cast<const s16x8*>(&Xsh[lo]);
      al[m] = *reinterpret_cast<const s16x8*>(&Xsl[lo]);
    }
#pragma unroll
    for (int n = 0; n < 4; n++) {
      const int off = packOff(wvi * 4 + n, kk8, l4, l15, 0);
      bh[n] = *reinterpret_cast<const s16x8*>(MTph + off);
      bl[n] = *reinterpret_cast<const s16x8*>(MTpl + off);
    }
#pragma unroll
    for (int m = 0; m < 2; m++)
#pragma unroll
      for (int n = 0; n < 4; n++) {
        acc[m][n] = MFMA16(ah[m], bh[n], acc[m][n], 0, 0, 0);
        acc[m][n] = MFMA16(ah[m], bl[n], acc[m][n], 0, 0, 0);
        acc[m][n] = MFMA16(al[m], bh[n], acc[m][n], 0, 0, 0);
      }
  }

#pragma unroll
  for (int m = 0; m < 2; m++)
#pragma unroll
    for (int n = 0; n < 4; n++) {
      const int col = wvi * 64 + n * 16 + l15;
      const int kk8c = col >> 5, gc = (col & 31) >> 3, ec = col & 7;
#pragma unroll
      for (int r = 0; r < 4; r++) {
        const int off = ((m * 8 + kk8c) * 4 + gc) * 128 + (l4 * 4 + r) * 8 + ec;
        const float v = acc[m][n][r];
        const unsigned short hb = f2bf(v);
        XMsh[off] = hb;
        XMsl[off] = f2bf(v - bfu(hb));
      }
    }
  __syncthreads();

#pragma unroll
  for (int it = 0; it < 4; it++) {
    const int ch = it * 256 + tid;
    const size_t gdst = (size_t)blk * 8192 + ch * 8;
    *reinterpret_cast<s16x8*>(XMh + gdst) = *reinterpret_cast<const s16x8*>(&XMsh[ch * 8]);
    *reinterpret_cast<s16x8*>(XMl + gdst) = *reinterpret_cast<const s16x8*>(&XMsl[ch * 8]);
    const int l15c = ch & 15, g3 = (ch >> 4) & 3, kk = (ch >> 6) & 7, mm = ch >> 9;
    const int lsrc = (mm * 16 + l15c) * 264 + kk * 32 + g3 * 8;
    *reinterpret_cast<s16x8*>(Xh + gdst) = *reinterpret_cast<const s16x8*>(&Xsh[lsrc]);
    *reinterpret_cast<s16x8*>(Xl + gdst) = *reinterpret_cast<const s16x8*>(&Xsl[lsrc]);
  }

  for (int m = 0; m < 2; m++) {
    f32x4 vac[4];
#pragma unroll
    for (int n = 0; n < 4; n++) vac[n] = (f32x4){0.f, 0.f, 0.f, 0.f};
    for (int kk8 = 0; kk8 < 8; kk8++) {
      const int lo = (m * 16 + l15) * 264 + kk8 * 32 + l4 * 8;
      const s16x8 ah = *reinterpret_cast<const s16x8*>(&Xsh[lo]);
      const s16x8 al = *reinterpret_cast<const s16x8*>(&Xsl[lo]);
#pragma unroll
      for (int n = 0; n < 4; n++) {
        const s16x8 bh = *reinterpret_cast<const s16x8*>(
            WvTp + packOff(wvi * 4 + n, kk8, l4, l15, 0));
        vac[n] = MFMA16(ah, bh, vac[n], 0, 0, 0);
        vac[n] = MFMA16(al, bh, vac[n], 0, 0, 0);
      }
    }
#pragma unroll
    for (int n = 0; n < 4; n++) {
      const int col = (wvi * 4 + n) * 16 + l15;
      const float bvv = bv[col];
#pragma unroll
      for (int r = 0; r < 4; r++)
        Vst[col * 24 + l4 * 4 + r] = f2bf(vac[n][r] + bvv);
    }
    __syncthreads();
    {
      const int gt = blk * 2 + m;
      const int bb = gt / 5, ct = gt - bb * 5;
      const unsigned short* src = &Vst[tid * 24];
      const s16x8 va = *reinterpret_cast<const s16x8*>(src);
      const s16x8 vb2 = *reinterpret_cast<const s16x8*>(src + 8);
      const size_t ga = ((size_t)bb * Hq + tid) * Cq + ct * 16;
      *reinterpret_cast<s16x8*>(Vt + ga) = va;
      *reinterpret_cast<s16x8*>(Vt + ga + 8) = vb2;
    }
    __syncthreads();
  }
}

// ---------------------------------------------------------------------------
// Attention v8: ONE WAVE per (b, i-tile w). 2560 blocks x 64 threads.
// Same arithmetic/data layout as attn5; barriers are now 1-wave (free) so
// waves run de-phased -> memory/MFMA overlap across blocks.
// XCD-chunk swizzle keeps the 5 blocks of one b on the same XCD (L2 share).
// ---------------------------------------------------------------------------
__global__ __launch_bounds__(64) void k_attn8(
    const unsigned short* __restrict__ XPh, const unsigned short* __restrict__ XPl,
    const unsigned short* __restrict__ XMh, const unsigned short* __restrict__ XMl,
    const unsigned short* __restrict__ Vt, const int* __restrict__ labels,
    const float* __restrict__ u, const float* __restrict__ vv,
    const float* __restrict__ cqk, const unsigned short* __restrict__ WoTp,
    const float* __restrict__ bo, float* __restrict__ out) {
  __shared__ unsigned short Pl_[16][104];   // 3328 B (wave-local P rows)
  __shared__ unsigned short Olds[16][264];  // 8448 B (wave-local O rows)
  __shared__ float vvs[80], lms[80];

  // XCD-chunked swizzle: consecutive mapped ids share an XCD; 5 blocks of one b
  // are consecutive in mapped space.
  const int blk = blockIdx.x;
  const int mapped = (blk & 7) * 320 + (blk >> 3);
  const int b = mapped / 5;
  const int w = mapped - b * 5;

  const int lane = threadIdx.x;
  const int l15 = lane & 15, g = lane >> 4;

  for (int j = lane; j < 80; j += 64) {
    vvs[j] = vv[b * Cq + j];
    lms[j] = (float)labels[b * Cq + j] * 0.8f + 0.2f;
  }

  f32x4 sacc[5];
#pragma unroll
  for (int mt = 0; mt < 5; mt++) sacc[mt] = (f32x4){0.f, 0.f, 0.f, 0.f};

  for (int kk8 = 0; kk8 < 8; kk8++) {
    const int offB = packOff(b * 5 + w, kk8, g, l15, 0);
    const s16x8 bh = *reinterpret_cast<const s16x8*>(XMh + offB);
    const s16x8 bl = *reinterpret_cast<const s16x8*>(XMl + offB);
#pragma unroll
    for (int mt = 0; mt < 5; mt++) {
      const int offA = packOff(b * 5 + mt, kk8, g, l15, 0);
      const s16x8 ah = *reinterpret_cast<const s16x8*>(XPh + offA);
      const s16x8 al = *reinterpret_cast<const s16x8*>(XPl + offA);
      sacc[mt] = MFMA16(ah, bh, sacc[mt], 0, 0, 0);
      sacc[mt] = MFMA16(ah, bl, sacc[mt], 0, 0, 0);
      sacc[mt] = MFMA16(al, bh, sacc[mt], 0, 0, 0);
    }
  }
  __syncthreads();   // 1-wave: just orders LDS stage vs reads (cheap)

  const int i = 16 * w + l15;
  const float ui = u[b * Cq + i];
  const float cq = *cqk;
  float p[5][4];
  float mx = -1e30f;
#pragma unroll
  for (int mt = 0; mt < 5; mt++)
#pragma unroll
    for (int r = 0; r < 4; r++) {
      const int j = 16 * mt + 4 * g + r;
      float sc = (sacc[mt][r] + ui + vvs[j] + cq) * SCALE;
      sc = (sc > THR) ? sc : 0.0f;
      sc *= lms[j];
      p[mt][r] = sc;
      mx = fmaxf(mx, sc);
    }
  mx = fmaxf(mx, __shfl_xor(mx, 16));
  mx = fmaxf(mx, __shfl_xor(mx, 32));
  float sum = 0.f;
#pragma unroll
  for (int mt = 0; mt < 5; mt++)
#pragma unroll
    for (int r = 0; r < 4; r++) {
      const float e = __expf(p[mt][r] - mx);
      p[mt][r] = e;
      sum += e;
    }
  sum += __shfl_xor(sum, 16);
  sum += __shfl_xor(sum, 32);
  const float inv = 1.0f / sum;

  // P rows are wave-local: local row = l15 (global i = 16w + l15)
#pragma unroll
  for (int mt = 0; mt < 5; mt++) {
    uint2 pk;
    pk.x = (unsigned)f2bf(p[mt][0] * inv) | ((unsigned)f2bf(p[mt][1] * inv) << 16);
    pk.y = (unsigned)f2bf(p[mt][2] * inv) | ((unsigned)f2bf(p[mt][3] * inv) << 16);
    *reinterpret_cast<uint2*>(reinterpret_cast<char*>(&Pl_[l15][0]) + 32 * mt + 8 * g) = pk;
  }
  if (lane < 32) {   // zero pad j in [80,96): 16 rows x 32B
    const uint4 z = {0u, 0u, 0u, 0u};
    *reinterpret_cast<uint4*>(
        reinterpret_cast<char*>(&Pl_[lane >> 1][0]) + 160 + 16 * (lane & 1)) = z;
  }
  __syncthreads();

  s16x8 pa[3];
#pragma unroll
  for (int ks = 0; ks < 3; ks++)
    pa[ks] = *reinterpret_cast<const s16x8*>(
        reinterpret_cast<const char*>(&Pl_[l15][0]) + 64 * ks + 16 * g);

  f32x4 oacc[16];
#pragma unroll
  for (int n = 0; n < 16; n++) oacc[n] = (f32x4){0.f, 0.f, 0.f, 0.f};

  const size_t vbase = (size_t)b * Hq * Cq;
#pragma unroll 4
  for (int n = 0; n < 16; n++) {
    const size_t hrow = vbase + (size_t)(16 * n + l15) * Cq + 8 * g;
#pragma unroll
    for (int ks = 0; ks < 3; ks++) {
      const s16x8 vb = *reinterpret_cast<const s16x8*>(Vt + hrow + 32 * ks);
      oacc[n] = MFMA16(pa[ks], vb, oacc[n], 0, 0, 0);
    }
  }

  // O rows wave-local: local row = 4g + r (global 16w + 4g + r)
#pragma unroll
  for (int n = 0; n < 16; n++)
#pragma unroll
    for (int r = 0; r < 4; r++)
      Olds[4 * g + r][16 * n + l15] = f2bf(oacc[n][r]);
  __syncthreads();

  f32x4 acc2[16];
#pragma unroll
  for (int n = 0; n < 16; n++) acc2[n] = (f32x4){0.f, 0.f, 0.f, 0.f};

  for (int ks = 0; ks < 8; ks++) {
    const s16x8 af = *reinterpret_cast<const s16x8*>(
        reinterpret_cast<const char*>(&Olds[l15][0]) + 64 * ks + 16 * g);
#pragma unroll
    for (int n = 0; n < 16; n++) {
      const s16x8 bf = *reinterpret_cast<const s16x8*>(WoTp + packOff(n, ks, g, l15, 0));
      acc2[n] = MFMA16(af, bf, acc2[n], 0, 0, 0);
    }
  }

#pragma unroll
  for (int n = 0; n < 16; n++) {
    const float bov = bo[16 * n + l15];
#pragma unroll
    for (int r = 0; r < 4; r++)
      out[((size_t)b * Cq + 16 * w + 4 * g + r) * Hq + 16 * n + l15] =
          acc2[n][r] + bov;
  }
}

// ---------------------------------------------------------------------------
extern "C" void kernel_launch(void* const* d_in, const int* in_sizes, int n_in,
                              void* d_out, int out_size, void* d_ws, size_t ws_size,
                              hipStream_t stream) {
  const float* x   = (const float*)d_in[0];
  const float* vf  = (const float*)d_in[1];
  const int*   lab = (const int*)d_in[2];
  const float* Wp  = (const float*)d_in[3];
  const float* bp  = (const float*)d_in[4];
  const float* gp  = (const float*)d_in[5];
  const float* bep = (const float*)d_in[6];
  const float* Wc  = (const float*)d_in[7];
  const float* bc  = (const float*)d_in[8];
  const float* gc  = (const float*)d_in[9];
  const float* bec = (const float*)d_in[10];
  const float* Wq  = (const float*)d_in[11];
  const float* bq_ = (const float*)d_in[12];
  const float* Wk  = (const float*)d_in[13];
  const float* bk_ = (const float*)d_in[14];
  const float* Wv  = (const float*)d_in[15];
  const float* bv_ = (const float*)d_in[16];
  const float* Wo  = (const float*)d_in[17];
  const float* bo_ = (const float*)d_in[18];
  float* out = (float*)d_out;
  (void)ws_size; (void)in_sizes; (void)n_in; (void)out_size;

  char* W = (char*)d_ws;
  unsigned short* Xh    = (unsigned short*)(W + 0);           // 20,971,520 (linear X', repacked in-place)
  unsigned short* Xl    = (unsigned short*)(W + 20971520);    // 20,971,520
  unsigned short* WcTph = (unsigned short*)(W + 41943040);    // 10,485,760
  unsigned short* WcTpl = (unsigned short*)(W + 52428800);    // 10,485,760
  unsigned short* XMh   = (unsigned short*)(W + 41943040);    // 20,971,520 (aliases WcT, dead after gemm1f)
  unsigned short* XMl   = (unsigned short*)(W + 62914560);    // 20,971,520
  unsigned short* Vt    = (unsigned short*)(W + 83886080);    // 20,971,520  [b][h][c]
  unsigned short* visPh = (unsigned short*)(W + 104857600);   // 262,144
  unsigned short* visPl = (unsigned short*)(W + 105119744);   // 262,144
  unsigned short* MTph  = (unsigned short*)(W + 105381888);   // 131,072
  unsigned short* MTpl  = (unsigned short*)(W + 105512960);   // 131,072
  unsigned short* WvTp  = (unsigned short*)(W + 105644032);   // 131,072
  unsigned short* WoTp  = (unsigned short*)(W + 105775104);   // 131,072
  float* w1  = (float*)(W + 105906176);                       // 1,024
  float* w2  = (float*)(W + 105907200);                       // 1,024
  float* cqk = (float*)(W + 105908224);                       // 256
  float* u   = (float*)(W + 105908480);                       // 163,840
  float* vvv = (float*)(W + 106072320);                       // 163,840 -> end 106,236,160

  k_setup<<<1792, 256, 0, stream>>>(vf, Wp, bp, gp, bep, visPh, visPl,
                                    Wq, Wk, bq_, bk_, MTph, MTpl, w1, w2, cqk,
                                    Wc, Wv, Wo, WcTph, WcTpl, WvTp, WoTp);
  k_gemm1f<<<1280, 256, 0, stream>>>(visPh, visPl, WcTph, WcTpl, x, bc, gc, bec,
                                     w1, w2, Xh, Xl, u, vvv);
  k_gemm2p<<<1280, 256, 0, stream>>>(Xh, Xl, MTph, MTpl, WvTp, bv_,
                                     XMh, XMl, Vt);
  k_attn8<<<2560, 64, 0, stream>>>(Xh, Xl, XMh, XMl, Vt, lab, u, vvv, cqk,
                                   WoTp, bo_, out);
}

// Round 14
// 192.901 us; speedup vs baseline: 1.0840x; 1.0840x over previous
//
#include <hip/hip_runtime.h>
#include <hip/hip_bf16.h>
#include <math.h>

#define Bq 512
#define Cq 80
#define Fq 768
#define Hq 256

constexpr float EPS   = 1e-5f;
constexpr float THR   = 0.5f;
constexpr float SCALE = 0.0625f;   // 1/sqrt(256)

using f32x4 = __attribute__((ext_vector_type(4))) float;
using s16x8 = __attribute__((ext_vector_type(8))) short;
using s16x4 = __attribute__((ext_vector_type(4))) short;

#define MFMA16 __builtin_amdgcn_mfma_f32_16x16x32_bf16

// Fragment-packed layout (A rows=M / B rows=N), addr in elements:
//   ((tile*8 + kk8)*4 + g)*128 + l15*8 + e
// tile = row/16, l15 = row%16, kk8 = k/32, g = (k%32)/8, e = k%8.

__device__ __forceinline__ float waveReduceSum(float v) {
#pragma unroll
  for (int m = 32; m >= 1; m >>= 1) v += __shfl_xor(v, m);
  return v;
}

__device__ __forceinline__ float bfu(unsigned short v) {
  return __uint_as_float(((unsigned)v) << 16);
}

__device__ __forceinline__ unsigned short f2bf(float f) {
  __hip_bfloat16 h = __float2bfloat16(f);   // RNE
  return *reinterpret_cast<unsigned short*>(&h);
}

__device__ __forceinline__ int packOff(int tile, int kk8, int g, int l15, int e) {
  return ((tile * 8 + kk8) * 4 + g) * 128 + l15 * 8 + e;
}

// ---------------------------------------------------------------------------
// K_setup (merged): blocks 0..511 visproj | 512..767 matmulM | 768..1791 prep
// ---------------------------------------------------------------------------
__global__ __launch_bounds__(256) void k_setup(
    const float* __restrict__ vf, const float* __restrict__ Wp,
    const float* __restrict__ bp, const float* __restrict__ gp,
    const float* __restrict__ bep,
    unsigned short* __restrict__ visPh, unsigned short* __restrict__ visPl,
    const float* __restrict__ Wq, const float* __restrict__ Wk,
    const float* __restrict__ bq, const float* __restrict__ bk,
    unsigned short* __restrict__ MTph, unsigned short* __restrict__ MTpl,
    float* __restrict__ w1, float* __restrict__ w2, float* __restrict__ cqk,
    const float* __restrict__ Wc, const float* __restrict__ Wv,
    const float* __restrict__ Wo,
    unsigned short* __restrict__ WcTph, unsigned short* __restrict__ WcTpl,
    unsigned short* __restrict__ WvTp, unsigned short* __restrict__ WoTp) {
  __shared__ float smA[Fq];
  __shared__ float red[4], redB[4], redC[4];
  const int blk = blockIdx.x;

  if (blk < 512) {
    // ---- visproj: vis = relu(LN(vf @ Wp + bp)) -> packed-A hi/lo ----
    const int b = blk, h = threadIdx.x;
    for (int i = h; i < Fq; i += 256) smA[i] = vf[b * Fq + i];
    __syncthreads();
    float acc = bp[h];
    for (int f = 0; f < Fq; f++) acc = fmaf(smA[f], Wp[f * Hq + h], acc);
    const int w = h >> 6, lane = h & 63;
    float s = waveReduceSum(acc);
    if (lane == 0) red[w] = s;
    __syncthreads();
    const float mean = (red[0] + red[1] + red[2] + red[3]) * (1.0f / Hq);
    __syncthreads();
    const float d = acc - mean;
    s = waveReduceSum(d * d);
    if (lane == 0) red[w] = s;
    __syncthreads();
    const float var = (red[0] + red[1] + red[2] + red[3]) * (1.0f / Hq);
    float y = d * rsqrtf(var + EPS) * gp[h] + bep[h];
    y = fmaxf(y, 0.0f);
    const unsigned short hb = f2bf(y);
    const int off = packOff(b >> 4, h >> 5, (h & 31) >> 3, b & 15, h & 7);
    visPh[off] = hb;
    visPl[off] = f2bf(y - bfu(hb));
  } else if (blk < 768) {
    // ---- matmulM: M = Wq@Wk^T -> packed-B hi/lo; w1,w2,cqk ----
    const int i = blk - 512, j = threadIdx.x;
    const int wv = j >> 6, lane = j & 63;
    smA[j] = Wq[i * Hq + j];
    __syncthreads();
    float acc = 0.f;
    const float* wkr = Wk + (size_t)j * Hq;
    for (int h = 0; h < Hq; h += 4) {
      const float4 a = *reinterpret_cast<const float4*>(&smA[h]);
      const float4 bb = *reinterpret_cast<const float4*>(&wkr[h]);
      acc = fmaf(a.x, bb.x, fmaf(a.y, bb.y, fmaf(a.z, bb.z, fmaf(a.w, bb.w, acc))));
    }
    const unsigned short hb = f2bf(acc);
    const int off = packOff(j >> 4, i >> 5, (i & 31) >> 3, j & 15, i & 7);
    MTph[off] = hb;
    MTpl[off] = f2bf(acc - bfu(hb));
    float p1 = smA[j] * bk[j];
    float p2 = Wk[(size_t)i * Hq + j] * bq[j];
    float p3 = bq[j] * bk[j];
    p1 = waveReduceSum(p1);
    p2 = waveReduceSum(p2);
    p3 = waveReduceSum(p3);
    if (lane == 0) { red[wv] = p1; redB[wv] = p2; redC[wv] = p3; }
    __syncthreads();
    if (j == 0) {
      w1[i] = red[0] + red[1] + red[2] + red[3];
      w2[i] = redB[0] + redB[1] + redB[2] + redB[3];
      if (i == 0) *cqk = redC[0] + redC[1] + redC[2] + redC[3];
    }
  } else {
    // ---- prep: pack Wc (hi/lo), Wv (hi), Wo (hi) into B-frag layout ----
    const int NWc = Cq * 32 * 256;
    const int NTOT = NWc + 2 * 32 * 256;
    for (int idx = (blk - 768) * 256 + threadIdx.x; idx < NTOT; idx += 1024 * 256) {
      if (idx < NWc) {
        const int c = idx >> 13, k8 = (idx >> 8) & 31, n = idx & 255;
        const float* src = Wc + (size_t)c * 65536 + (size_t)k8 * 8 * 256 + n;
        s16x8 hh, ll;
#pragma unroll
        for (int e = 0; e < 8; e++) {
          const float v = src[e * 256];
          const unsigned short hb = f2bf(v);
          hh[e] = (short)hb;
          ll[e] = (short)f2bf(v - bfu(hb));
        }
        const int off = c * 65536 + packOff(n >> 4, k8 >> 2, k8 & 3, n & 15, 0);
        *reinterpret_cast<s16x8*>(WcTph + off) = hh;
        *reinterpret_cast<s16x8*>(WcTpl + off) = ll;
      } else {
        const int r = idx - NWc;
        const int which = r >> 13;           // 0 = Wv, 1 = Wo
        const int r2 = r & 8191;
        const int k8 = r2 >> 8, n = r2 & 255;
        const float* src = (which == 0 ? Wv : Wo) + (size_t)k8 * 8 * 256 + n;
        s16x8 hh;
#pragma unroll
        for (int e = 0; e < 8; e++) hh[e] = (short)f2bf(src[e * 256]);
        const int off = packOff(n >> 4, k8 >> 2, k8 & 3, n & 15, 0);
        *reinterpret_cast<s16x8*>((which == 0 ? WvTp : WoTp) + off) = hh;
      }
    }
  }
}

// ---------------------------------------------------------------------------
// GEMM1: Z = vis@Wc[c]+bc (split-3 MFMA) -> LN -> relu -> +x -> X'
// X' written LINEAR ([r][256], coalesced rows); u = X'.w1, vv = X'.w2.
// grid 1280 (XCD-chunked), block 256 = 4 waves, 32 b-rows x 1 c.
// ---------------------------------------------------------------------------
__global__ __launch_bounds__(256) void k_gemm1f(
    const unsigned short* __restrict__ visPh, const unsigned short* __restrict__ visPl,
    const unsigned short* __restrict__ WcTph, const unsigned short* __restrict__ WcTpl,
    const float* __restrict__ x, const float* __restrict__ bc,
    const float* __restrict__ gc, const float* __restrict__ bec,
    const float* __restrict__ w1, const float* __restrict__ w2,
    unsigned short* __restrict__ Xgh, unsigned short* __restrict__ Xgl,
    float* __restrict__ u, float* __restrict__ vv) {
  const int blk = blockIdx.x;
  const int mapped = (blk & 7) * 160 + (blk >> 3);
  const int c = mapped >> 4;
  const int bx = mapped & 15;
  const int b0 = bx * 32;
  const int tid = threadIdx.x;
  const int wvi = tid >> 6, lane = tid & 63;
  const int l15 = lane & 15, l4 = lane >> 4;

  __shared__ float Zs[32][268];   // 268 pad: kills l4-lane same-bank conflicts

  f32x4 acc[2][4];
#pragma unroll
  for (int m = 0; m < 2; m++)
#pragma unroll
    for (int n = 0; n < 4; n++) acc[m][n] = (f32x4){0.f, 0.f, 0.f, 0.f};

  const unsigned short* Bh = WcTph + (size_t)c * 65536;
  const unsigned short* Bl = WcTpl + (size_t)c * 65536;

  for (int kk8 = 0; kk8 < 8; kk8++) {
    s16x8 ah[2], al[2], bh[4], bl[4];
#pragma unroll
    for (int m = 0; m < 2; m++) {
      const int off = packOff(bx * 2 + m, kk8, l4, l15, 0);
      ah[m] = *reinterpret_cast<const s16x8*>(visPh + off);
      al[m] = *reinterpret_cast<const s16x8*>(visPl + off);
    }
#pragma unroll
    for (int n = 0; n < 4; n++) {
      const int off = packOff(wvi * 4 + n, kk8, l4, l15, 0);
      bh[n] = *reinterpret_cast<const s16x8*>(Bh + off);
      bl[n] = *reinterpret_cast<const s16x8*>(Bl + off);
    }
#pragma unroll
    for (int m = 0; m < 2; m++)
#pragma unroll
      for (int n = 0; n < 4; n++) {
        acc[m][n] = MFMA16(ah[m], bh[n], acc[m][n], 0, 0, 0);
        acc[m][n] = MFMA16(ah[m], bl[n], acc[m][n], 0, 0, 0);
        acc[m][n] = MFMA16(al[m], bh[n], acc[m][n], 0, 0, 0);
      }
  }

#pragma unroll
  for (int m = 0; m < 2; m++)
#pragma unroll
    for (int n = 0; n < 4; n++) {
      const int col = wvi * 64 + n * 16 + l15;
      const float bcv = bc[c * Hq + col];
#pragma unroll
      for (int r = 0; r < 4; r++)
        Zs[m * 16 + l4 * 4 + r][col] = acc[m][n][r] + bcv;
    }
  __syncthreads();

  // ---- LN + relu + add x -> linear hi/lo write; u/vv dot products ----
  const int row = tid >> 3, sub = tid & 7;
  const int grow = b0 + row;
  const size_t xrow = ((size_t)grow * Cq + c) * Hq;
  float zz[32];
  float sum = 0.f, sumsq = 0.f;
#pragma unroll
  for (int kq = 0; kq < 8; kq++) {
    const float4 z = *reinterpret_cast<const float4*>(&Zs[row][sub * 4 + kq * 32]);
    zz[4 * kq + 0] = z.x; zz[4 * kq + 1] = z.y;
    zz[4 * kq + 2] = z.z; zz[4 * kq + 3] = z.w;
    sum += z.x + z.y + z.z + z.w;
    sumsq += z.x * z.x + z.y * z.y + z.z * z.z + z.w * z.w;
  }
#pragma unroll
  for (int msk = 4; msk >= 1; msk >>= 1) {
    sum += __shfl_xor(sum, msk);
    sumsq += __shfl_xor(sumsq, msk);
  }
  const float mean = sum * (1.0f / Hq);
  const float var = sumsq * (1.0f / Hq) - mean * mean;
  const float inv = rsqrtf(var + EPS);

  float pu = 0.f, pv = 0.f;
#pragma unroll
  for (int kq = 0; kq < 8; kq++) {
    const int col = sub * 4 + kq * 32;
    const float4 xv = *reinterpret_cast<const float4*>(&x[xrow + col]);
    const float xr[4] = {xv.x, xv.y, xv.z, xv.w};
    s16x4 hh, ll;
#pragma unroll
    for (int e = 0; e < 4; e++) {
      float tt = (zz[4 * kq + e] - mean) * inv * gc[c * Hq + col + e] + bec[c * Hq + col + e];
      tt = fmaxf(tt, 0.f);
      const float xp = xr[e] + tt;
      const unsigned short hb2 = f2bf(xp);
      hh[e] = (short)hb2;
      ll[e] = (short)f2bf(xp - bfu(hb2));
      pu = fmaf(xp, w1[col + e], pu);
      pv = fmaf(xp, w2[col + e], pv);
    }
    *reinterpret_cast<s16x4*>(Xgh + xrow + col) = hh;   // linear, coalesced
    *reinterpret_cast<s16x4*>(Xgl + xrow + col) = ll;
  }
#pragma unroll
  for (int msk = 4; msk >= 1; msk >>= 1) {
    pu += __shfl_xor(pu, msk);
    pv += __shfl_xor(pv, msk);
  }
  if (sub == 0) {
    u[(size_t)grow * Cq + c] = pu;
    vv[(size_t)grow * Cq + c] = pv;
  }
}

// ---------------------------------------------------------------------------
// GEMM2 (repack hub): per block 32 linear X' rows -> LDS, then
//  (1) XM = X'@M (split-3) -> LDS packed stage -> coalesced packed write
//  (2) packed X' written IN-PLACE over the linear X' bytes (aliased Xh/Xl,
//      no __restrict__ on them)
//  (3) V = X'@Wv + bv (split-2) -> LDS transpose -> Vt[b][h][c] (32B runs)
// ---------------------------------------------------------------------------
__global__ __launch_bounds__(256) void k_gemm2p(
    unsigned short* Xh, unsigned short* Xl,       // aliased on purpose
    const unsigned short* __restrict__ MTph, const unsigned short* __restrict__ MTpl,
    const unsigned short* __restrict__ WvTp, const float* __restrict__ bv,
    unsigned short* __restrict__ XMh, unsigned short* __restrict__ XMl,
    unsigned short* __restrict__ Vt) {
  __shared__ __attribute__((aligned(16))) unsigned short Xsh[32 * 264];
  __shared__ __attribute__((aligned(16))) unsigned short Xsl[32 * 264];
  __shared__ __attribute__((aligned(16))) unsigned short XMsh[8192];
  __shared__ __attribute__((aligned(16))) unsigned short XMsl[8192];
  __shared__ __attribute__((aligned(16))) unsigned short Vst[256 * 24];

  const int blk = blockIdx.x;
  const int r0 = blk * 32;
  const int tid = threadIdx.x;
  const int wvi = tid >> 6, lane = tid & 63;
  const int l15 = lane & 15, l4 = lane >> 4;

  // ---- stage 32 linear rows (hi+lo) into LDS, 264-padded ----
#pragma unroll
  for (int it = 0; it < 4; it++) {
    const int ch = it * 256 + tid;            // 1024 chunks of 16B
    const int rr = ch >> 5, cc = ch & 31;
    const size_t gsrc = (size_t)(r0 + rr) * Hq + cc * 8;
    *reinterpret_cast<s16x8*>(&Xsh[rr * 264 + cc * 8]) =
        *reinterpret_cast<const s16x8*>(Xh + gsrc);
    *reinterpret_cast<s16x8*>(&Xsl[rr * 264 + cc * 8]) =
        *reinterpret_cast<const s16x8*>(Xl + gsrc);
  }
  __syncthreads();

  // ---- XM = X' @ M (split-3), A from LDS, B packed global ----
  f32x4 acc[2][4];
#pragma unroll
  for (int m = 0; m < 2; m++)
#pragma unroll
    for (int n = 0; n < 4; n++) acc[m][n] = (f32x4){0.f, 0.f, 0.f, 0.f};

  for (int kk8 = 0; kk8 < 8; kk8++) {
    s16x8 ah[2], al[2], bh[4], bl[4];
#pragma unroll
    for (int m = 0; m < 2; m++) {
      const int lo = (m * 16 + l15) * 264 + kk8 * 32 + l4 * 8;
      ah[m] = *reinterpret_cast<const s16x8*>(&Xsh[lo]);
      al[m] = *reinterpret_cast<const s16x8*>(&Xsl[lo]);
    }
#pragma unroll
    for (int n = 0; n < 4; n++) {
      const int off = packOff(wvi * 4 + n, kk8, l4, l15, 0);
      bh[n] = *reinterpret_cast<const s16x8*>(MTph + off);
      bl[n] = *reinterpret_cast<const s16x8*>(MTpl + off);
    }
#pragma unroll
    for (int m = 0; m < 2; m++)
#pragma unroll
      for (int n = 0; n < 4; n++) {
        acc[m][n] = MFMA16(ah[m], bh[n], acc[m][n], 0, 0, 0);
        acc[m][n] = MFMA16(ah[m], bl[n], acc[m][n], 0, 0, 0);
        acc[m][n] = MFMA16(al[m], bh[n], acc[m][n], 0, 0, 0);
      }
  }

  // scatter into LDS packed image of the 2 tiles
#pragma unroll
  for (int m = 0; m < 2; m++)
#pragma unroll
    for (int n = 0; n < 4; n++) {
      const int col = wvi * 64 + n * 16 + l15;
      const int kk8c = col >> 5, gc = (col & 31) >> 3, ec = col & 7;
#pragma unroll
      for (int r = 0; r < 4; r++) {
        const int off = ((m * 8 + kk8c) * 4 + gc) * 128 + (l4 * 4 + r) * 8 + ec;
        const float v = acc[m][n][r];
        const unsigned short hb = f2bf(v);
        XMsh[off] = hb;
        XMsl[off] = f2bf(v - bfu(hb));
      }
    }
  __syncthreads();

  // coalesced flush: XM packed + X' packed (overwrites this block's linear X bytes)
#pragma unroll
  for (int it = 0; it < 4; it++) {
    const int ch = it * 256 + tid;            // 1024 chunks of 16B
    const size_t gdst = (size_t)blk * 8192 + ch * 8;
    *reinterpret_cast<s16x8*>(XMh + gdst) = *reinterpret_cast<const s16x8*>(&XMsh[ch * 8]);
    *reinterpret_cast<s16x8*>(XMl + gdst) = *reinterpret_cast<const s16x8*>(&XMsl[ch * 8]);
    // packed X' chunk ch -> (mm, kk, g, l15c)
    const int l15c = ch & 15, g3 = (ch >> 4) & 3, kk = (ch >> 6) & 7, mm = ch >> 9;
    const int lsrc = (mm * 16 + l15c) * 264 + kk * 32 + g3 * 8;
    *reinterpret_cast<s16x8*>(Xh + gdst) = *reinterpret_cast<const s16x8*>(&Xsh[lsrc]);
    *reinterpret_cast<s16x8*>(Xl + gdst) = *reinterpret_cast<const s16x8*>(&Xsl[lsrc]);
  }

  // ---- V = X' @ Wv + bv (split-2), per tile; LDS transpose -> Vt ----
  for (int m = 0; m < 2; m++) {
    f32x4 vac[4];
#pragma unroll
    for (int n = 0; n < 4; n++) vac[n] = (f32x4){0.f, 0.f, 0.f, 0.f};
    for (int kk8 = 0; kk8 < 8; kk8++) {
      const int lo = (m * 16 + l15) * 264 + kk8 * 32 + l4 * 8;
      const s16x8 ah = *reinterpret_cast<const s16x8*>(&Xsh[lo]);
      const s16x8 al = *reinterpret_cast<const s16x8*>(&Xsl[lo]);
#pragma unroll
      for (int n = 0; n < 4; n++) {
        const s16x8 bh = *reinterpret_cast<const s16x8*>(
            WvTp + packOff(wvi * 4 + n, kk8, l4, l15, 0));
        vac[n] = MFMA16(ah, bh, vac[n], 0, 0, 0);
        vac[n] = MFMA16(al, bh, vac[n], 0, 0, 0);
      }
    }
#pragma unroll
    for (int n = 0; n < 4; n++) {
      const int col = (wvi * 4 + n) * 16 + l15;
      const float bvv = bv[col];
#pragma unroll
      for (int r = 0; r < 4; r++)
        Vst[col * 24 + l4 * 4 + r] = f2bf(vac[n][r] + bvv);
    }
    __syncthreads();
    {
      const int gt = blk * 2 + m;
      const int bb = gt / 5, ct = gt - bb * 5;
      const unsigned short* src = &Vst[tid * 24];
      const s16x8 va = *reinterpret_cast<const s16x8*>(src);
      const s16x8 vb2 = *reinterpret_cast<const s16x8*>(src + 8);
      const size_t ga = ((size_t)bb * Hq + tid) * Cq + ct * 16;
      *reinterpret_cast<s16x8*>(Vt + ga) = va;
      *reinterpret_cast<s16x8*>(Vt + ga + 8) = vb2;
    }
    __syncthreads();
  }
}

// ---------------------------------------------------------------------------
// Attention (split-3 scores) + PV + fused out-proj. One block per b, 5 waves.
// (verbatim: the 194.2us-measured version)
// ---------------------------------------------------------------------------
__global__ __launch_bounds__(320) void k_attn5(
    const unsigned short* __restrict__ XPh, const unsigned short* __restrict__ XPl,
    const unsigned short* __restrict__ XMh, const unsigned short* __restrict__ XMl,
    const unsigned short* __restrict__ Vt, const int* __restrict__ labels,
    const float* __restrict__ u, const float* __restrict__ vv,
    const float* __restrict__ cqk, const unsigned short* __restrict__ WoTp,
    const float* __restrict__ bo, float* __restrict__ out) {
  __shared__ unsigned short Pl_[80][104];   // 16640 B
  __shared__ unsigned short Olds[80][264];  // 42240 B
  __shared__ float us[80], vvs[80], lms[80];

  const int b = blockIdx.x, t = threadIdx.x;
  const int w = t >> 6, lane = t & 63;
  const int l15 = lane & 15, g = lane >> 4;

  if (t < 80) {
    us[t] = u[b * Cq + t];
    vvs[t] = vv[b * Cq + t];
    lms[t] = (float)labels[b * Cq + t] * 0.8f + 0.2f;
  }

  f32x4 sacc[5];
#pragma unroll
  for (int mt = 0; mt < 5; mt++) sacc[mt] = (f32x4){0.f, 0.f, 0.f, 0.f};

  for (int kk8 = 0; kk8 < 8; kk8++) {
    const int offB = packOff(b * 5 + w, kk8, g, l15, 0);
    const s16x8 bh = *reinterpret_cast<const s16x8*>(XMh + offB);
    const s16x8 bl = *reinterpret_cast<const s16x8*>(XMl + offB);
#pragma unroll
    for (int mt = 0; mt < 5; mt++) {
      const int offA = packOff(b * 5 + mt, kk8, g, l15, 0);
      const s16x8 ah = *reinterpret_cast<const s16x8*>(XPh + offA);
      const s16x8 al = *reinterpret_cast<const s16x8*>(XPl + offA);
      sacc[mt] = MFMA16(ah, bh, sacc[mt], 0, 0, 0);
      sacc[mt] = MFMA16(ah, bl, sacc[mt], 0, 0, 0);
      sacc[mt] = MFMA16(al, bh, sacc[mt], 0, 0, 0);
    }
  }
  __syncthreads();   // us/vvs/lms ready

  const int i = 16 * w + l15;
  const float ui = us[i];
  const float cq = *cqk;
  float p[5][4];
  float mx = -1e30f;
#pragma unroll
  for (int mt = 0; mt < 5; mt++)
#pragma unroll
    for (int r = 0; r < 4; r++) {
      const int j = 16 * mt + 4 * g + r;
      float sc = (sacc[mt][r] + ui + vvs[j] + cq) * SCALE;
      sc = (sc > THR) ? sc : 0.0f;
      sc *= lms[j];
      p[mt][r] = sc;
      mx = fmaxf(mx, sc);
    }
  mx = fmaxf(mx, __shfl_xor(mx, 16));
  mx = fmaxf(mx, __shfl_xor(mx, 32));
  float sum = 0.f;
#pragma unroll
  for (int mt = 0; mt < 5; mt++)
#pragma unroll
    for (int r = 0; r < 4; r++) {
      const float e = __expf(p[mt][r] - mx);
      p[mt][r] = e;
      sum += e;
    }
  sum += __shfl_xor(sum, 16);
  sum += __shfl_xor(sum, 32);
  const float inv = 1.0f / sum;

#pragma unroll
  for (int mt = 0; mt < 5; mt++) {
    uint2 pk;
    pk.x = (unsigned)f2bf(p[mt][0] * inv) | ((unsigned)f2bf(p[mt][1] * inv) << 16);
    pk.y = (unsigned)f2bf(p[mt][2] * inv) | ((unsigned)f2bf(p[mt][3] * inv) << 16);
    *reinterpret_cast<uint2*>(reinterpret_cast<char*>(&Pl_[i][0]) + 32 * mt + 8 * g) = pk;
  }
  if (t < 160) {   // zero pad j in [80,96)
    const uint4 z = {0u, 0u, 0u, 0u};
    *reinterpret_cast<uint4*>(reinterpret_cast<char*>(&Pl_[t >> 1][0]) + 160 + 16 * (t & 1)) = z;
  }
  __syncthreads();

  s16x8 pa[3];
#pragma unroll
  for (int ks = 0; ks < 3; ks++)
    pa[ks] = *reinterpret_cast<const s16x8*>(
        reinterpret_cast<const char*>(&Pl_[i][0]) + 64 * ks + 16 * g);

  f32x4 oacc[16];
#pragma unroll
  for (int n = 0; n < 16; n++) oacc[n] = (f32x4){0.f, 0.f, 0.f, 0.f};

  const size_t vbase = (size_t)b * Hq * Cq;
#pragma unroll 4
  for (int n = 0; n < 16; n++) {
    const size_t hrow = vbase + (size_t)(16 * n + l15) * Cq + 8 * g;
#pragma unroll
    for (int ks = 0; ks < 3; ks++) {
      const s16x8 vb = *reinterpret_cast<const s16x8*>(Vt + hrow + 32 * ks);
      oacc[n] = MFMA16(pa[ks], vb, oacc[n], 0, 0, 0);
    }
  }

#pragma unroll
  for (int n = 0; n < 16; n++)
#pragma unroll
    for (int r = 0; r < 4; r++)
      Olds[16 * w + 4 * g + r][16 * n + l15] = f2bf(oacc[n][r]);
  // wave-local rows only: no barrier needed

  f32x4 acc2[16];
#pragma unroll
  for (int n = 0; n < 16; n++) acc2[n] = (f32x4){0.f, 0.f, 0.f, 0.f};

  for (int ks = 0; ks < 8; ks++) {
    const s16x8 af = *reinterpret_cast<const s16x8*>(
        reinterpret_cast<const char*>(&Olds[16 * w + l15][0]) + 64 * ks + 16 * g);
#pragma unroll
    for (int n = 0; n < 16; n++) {
      const s16x8 bf = *reinterpret_cast<const s16x8*>(WoTp + packOff(n, ks, g, l15, 0));
      acc2[n] = MFMA16(af, bf, acc2[n], 0, 0, 0);
    }
  }

#pragma unroll
  for (int n = 0; n < 16; n++) {
    const float bov = bo[16 * n + l15];
#pragma unroll
    for (int r = 0; r < 4; r++)
      out[((size_t)b * Cq + 16 * w + 4 * g + r) * Hq + 16 * n + l15] =
          acc2[n][r] + bov;
  }
}

// ---------------------------------------------------------------------------
extern "C" void kernel_launch(void* const* d_in, const int* in_sizes, int n_in,
                              void* d_out, int out_size, void* d_ws, size_t ws_size,
                              hipStream_t stream) {
  const float* x   = (const float*)d_in[0];
  const float* vf  = (const float*)d_in[1];
  const int*   lab = (const int*)d_in[2];
  const float* Wp  = (const float*)d_in[3];
  const float* bp  = (const float*)d_in[4];
  const float* gp  = (const float*)d_in[5];
  const float* bep = (const float*)d_in[6];
  const float* Wc  = (const float*)d_in[7];
  const float* bc  = (const float*)d_in[8];
  const float* gc  = (const float*)d_in[9];
  const float* bec = (const float*)d_in[10];
  const float* Wq  = (const float*)d_in[11];
  const float* bq_ = (const float*)d_in[12];
  const float* Wk  = (const float*)d_in[13];
  const float* bk_ = (const float*)d_in[14];
  const float* Wv  = (const float*)d_in[15];
  const float* bv_ = (const float*)d_in[16];
  const float* Wo  = (const float*)d_in[17];
  const float* bo_ = (const float*)d_in[18];
  float* out = (float*)d_out;
  (void)ws_size; (void)in_sizes; (void)n_in; (void)out_size;

  char* W = (char*)d_ws;
  unsigned short* Xh    = (unsigned short*)(W + 0);           // 20,971,520 (linear X', repacked in-place)
  unsigned short* Xl    = (unsigned short*)(W + 20971520);    // 20,971,520
  unsigned short* WcTph = (unsigned short*)(W + 41943040);    // 10,485,760
  unsigned short* WcTpl = (unsigned short*)(W + 52428800);    // 10,485,760
  unsigned short* XMh   = (unsigned short*)(W + 41943040);    // 20,971,520 (aliases WcT, dead after gemm1f)
  unsigned short* XMl   = (unsigned short*)(W + 62914560);    // 20,971,520
  unsigned short* Vt    = (unsigned short*)(W + 83886080);    // 20,971,520  [b][h][c]
  unsigned short* visPh = (unsigned short*)(W + 104857600);   // 262,144
  unsigned short* visPl = (unsigned short*)(W + 105119744);   // 262,144
  unsigned short* MTph  = (unsigned short*)(W + 105381888);   // 131,072
  unsigned short* MTpl  = (unsigned short*)(W + 105512960);   // 131,072
  unsigned short* WvTp  = (unsigned short*)(W + 105644032);   // 131,072
  unsigned short* WoTp  = (unsigned short*)(W + 105775104);   // 131,072
  float* w1  = (float*)(W + 105906176);                       // 1,024
  float* w2  = (float*)(W + 105907200);                       // 1,024
  float* cqk = (float*)(W + 105908224);                       // 256
  float* u   = (float*)(W + 105908480);                       // 163,840
  float* vvv = (float*)(W + 106072320);                       // 163,840 -> end 106,236,160

  k_setup<<<1792, 256, 0, stream>>>(vf, Wp, bp, gp, bep, visPh, visPl,
                                    Wq, Wk, bq_, bk_, MTph, MTpl, w1, w2, cqk,
                                    Wc, Wv, Wo, WcTph, WcTpl, WvTp, WoTp);
  k_gemm1f<<<1280, 256, 0, stream>>>(visPh, visPl, WcTph, WcTpl, x, bc, gc, bec,
                                     w1, w2, Xh, Xl, u, vvv);
  k_gemm2p<<<1280, 256, 0, stream>>>(Xh, Xl, MTph, MTpl, WvTp, bv_,
                                     XMh, XMl, Vt);
  k_attn5<<<Bq, 320, 0, stream>>>(Xh, Xl, XMh, XMl, Vt, lab, u, vvv, cqk,
                                  WoTp, bo_, out);
}

// Round 15
// 188.288 us; speedup vs baseline: 1.1106x; 1.0245x over previous
//
#include <hip/hip_runtime.h>
#include <hip/hip_bf16.h>
#include <math.h>

#define Bq 512
#define Cq 80
#define Fq 768
#define Hq 256

constexpr float EPS   = 1e-5f;
constexpr float THR   = 0.5f;
constexpr float SCALE = 0.0625f;   // 1/sqrt(256)

using f32x4 = __attribute__((ext_vector_type(4))) float;
using s16x8 = __attribute__((ext_vector_type(8))) short;
using s16x4 = __attribute__((ext_vector_type(4))) short;

#define MFMA16 __builtin_amdgcn_mfma_f32_16x16x32_bf16

// Fragment-packed layout (A rows=M / B rows=N), addr in elements:
//   ((tile*8 + kk8)*4 + g)*128 + l15*8 + e
// tile = row/16, l15 = row%16, kk8 = k/32, g = (k%32)/8, e = k%8.
// One (tile,kk8) chunk = 512 contiguous ushort (1KB).

__device__ __forceinline__ float waveReduceSum(float v) {
#pragma unroll
  for (int m = 32; m >= 1; m >>= 1) v += __shfl_xor(v, m);
  return v;
}

__device__ __forceinline__ float bfu(unsigned short v) {
  return __uint_as_float(((unsigned)v) << 16);
}

__device__ __forceinline__ unsigned short f2bf(float f) {
  __hip_bfloat16 h = __float2bfloat16(f);   // RNE
  return *reinterpret_cast<unsigned short*>(&h);
}

__device__ __forceinline__ int packOff(int tile, int kk8, int g, int l15, int e) {
  return ((tile * 8 + kk8) * 4 + g) * 128 + l15 * 8 + e;
}

// ---------------------------------------------------------------------------
// K_setup (merged): blocks 0..511 visproj | 512..767 matmulM | 768..1791 prep
// ---------------------------------------------------------------------------
__global__ __launch_bounds__(256) void k_setup(
    const float* __restrict__ vf, const float* __restrict__ Wp,
    const float* __restrict__ bp, const float* __restrict__ gp,
    const float* __restrict__ bep,
    unsigned short* __restrict__ visPh, unsigned short* __restrict__ visPl,
    const float* __restrict__ Wq, const float* __restrict__ Wk,
    const float* __restrict__ bq, const float* __restrict__ bk,
    unsigned short* __restrict__ MTph, unsigned short* __restrict__ MTpl,
    float* __restrict__ w1, float* __restrict__ w2, float* __restrict__ cqk,
    const float* __restrict__ Wc, const float* __restrict__ Wv,
    const float* __restrict__ Wo,
    unsigned short* __restrict__ WcTph, unsigned short* __restrict__ WcTpl,
    unsigned short* __restrict__ WvTp, unsigned short* __restrict__ WoTp) {
  __shared__ float smA[Fq];
  __shared__ float red[4], redB[4], redC[4];
  const int blk = blockIdx.x;

  if (blk < 512) {
    // ---- visproj: vis = relu(LN(vf @ Wp + bp)) -> packed-A hi/lo ----
    const int b = blk, h = threadIdx.x;
    for (int i = h; i < Fq; i += 256) smA[i] = vf[b * Fq + i];
    __syncthreads();
    float acc = bp[h];
    for (int f = 0; f < Fq; f++) acc = fmaf(smA[f], Wp[f * Hq + h], acc);
    const int w = h >> 6, lane = h & 63;
    float s = waveReduceSum(acc);
    if (lane == 0) red[w] = s;
    __syncthreads();
    const float mean = (red[0] + red[1] + red[2] + red[3]) * (1.0f / Hq);
    __syncthreads();
    const float d = acc - mean;
    s = waveReduceSum(d * d);
    if (lane == 0) red[w] = s;
    __syncthreads();
    const float var = (red[0] + red[1] + red[2] + red[3]) * (1.0f / Hq);
    float y = d * rsqrtf(var + EPS) * gp[h] + bep[h];
    y = fmaxf(y, 0.0f);
    const unsigned short hb = f2bf(y);
    const int off = packOff(b >> 4, h >> 5, (h & 31) >> 3, b & 15, h & 7);
    visPh[off] = hb;
    visPl[off] = f2bf(y - bfu(hb));
  } else if (blk < 768) {
    // ---- matmulM: M = Wq@Wk^T -> packed-B hi/lo; w1,w2,cqk ----
    const int i = blk - 512, j = threadIdx.x;
    const int wv = j >> 6, lane = j & 63;
    smA[j] = Wq[i * Hq + j];
    __syncthreads();
    float acc = 0.f;
    const float* wkr = Wk + (size_t)j * Hq;
    for (int h = 0; h < Hq; h += 4) {
      const float4 a = *reinterpret_cast<const float4*>(&smA[h]);
      const float4 bb = *reinterpret_cast<const float4*>(&wkr[h]);
      acc = fmaf(a.x, bb.x, fmaf(a.y, bb.y, fmaf(a.z, bb.z, fmaf(a.w, bb.w, acc))));
    }
    const unsigned short hb = f2bf(acc);
    const int off = packOff(j >> 4, i >> 5, (i & 31) >> 3, j & 15, i & 7);
    MTph[off] = hb;
    MTpl[off] = f2bf(acc - bfu(hb));
    float p1 = smA[j] * bk[j];
    float p2 = Wk[(size_t)i * Hq + j] * bq[j];
    float p3 = bq[j] * bk[j];
    p1 = waveReduceSum(p1);
    p2 = waveReduceSum(p2);
    p3 = waveReduceSum(p3);
    if (lane == 0) { red[wv] = p1; redB[wv] = p2; redC[wv] = p3; }
    __syncthreads();
    if (j == 0) {
      w1[i] = red[0] + red[1] + red[2] + red[3];
      w2[i] = redB[0] + redB[1] + redB[2] + redB[3];
      if (i == 0) *cqk = redC[0] + redC[1] + redC[2] + redC[3];
    }
  } else {
    // ---- prep: pack Wc (hi/lo), Wv (hi), Wo (hi) into B-frag layout ----
    const int NWc = Cq * 32 * 256;
    const int NTOT = NWc + 2 * 32 * 256;
    for (int idx = (blk - 768) * 256 + threadIdx.x; idx < NTOT; idx += 1024 * 256) {
      if (idx < NWc) {
        const int c = idx >> 13, k8 = (idx >> 8) & 31, n = idx & 255;
        const float* src = Wc + (size_t)c * 65536 + (size_t)k8 * 8 * 256 + n;
        s16x8 hh, ll;
#pragma unroll
        for (int e = 0; e < 8; e++) {
          const float v = src[e * 256];
          const unsigned short hb = f2bf(v);
          hh[e] = (short)hb;
          ll[e] = (short)f2bf(v - bfu(hb));
        }
        const int off = c * 65536 + packOff(n >> 4, k8 >> 2, k8 & 3, n & 15, 0);
        *reinterpret_cast<s16x8*>(WcTph + off) = hh;
        *reinterpret_cast<s16x8*>(WcTpl + off) = ll;
      } else {
        const int r = idx - NWc;
        const int which = r >> 13;           // 0 = Wv, 1 = Wo
        const int r2 = r & 8191;
        const int k8 = r2 >> 8, n = r2 & 255;
        const float* src = (which == 0 ? Wv : Wo) + (size_t)k8 * 8 * 256 + n;
        s16x8 hh;
#pragma unroll
        for (int e = 0; e < 8; e++) hh[e] = (short)f2bf(src[e * 256]);
        const int off = packOff(n >> 4, k8 >> 2, k8 & 3, n & 15, 0);
        *reinterpret_cast<s16x8*>((which == 0 ? WvTp : WoTp) + off) = hh;
      }
    }
  }
}

// ---------------------------------------------------------------------------
// GEMM1: Z = vis@Wc[c]+bc (split-3 MFMA) -> LN -> relu -> +x -> X'
// X' written LINEAR ([r][256], coalesced rows); u = X'.w1, vv = X'.w2.
// grid 1280 (XCD-chunked), block 256 = 4 waves, 32 b-rows x 1 c.
// ---------------------------------------------------------------------------
__global__ __launch_bounds__(256) void k_gemm1f(
    const unsigned short* __restrict__ visPh, const unsigned short* __restrict__ visPl,
    const unsigned short* __restrict__ WcTph, const unsigned short* __restrict__ WcTpl,
    const float* __restrict__ x, const float* __restrict__ bc,
    const float* __restrict__ gc, const float* __restrict__ bec,
    const float* __restrict__ w1, const float* __restrict__ w2,
    unsigned short* __restrict__ Xgh, unsigned short* __restrict__ Xgl,
    float* __restrict__ u, float* __restrict__ vv) {
  const int blk = blockIdx.x;
  const int mapped = (blk & 7) * 160 + (blk >> 3);
  const int c = mapped >> 4;
  const int bx = mapped & 15;
  const int b0 = bx * 32;
  const int tid = threadIdx.x;
  const int wvi = tid >> 6, lane = tid & 63;
  const int l15 = lane & 15, l4 = lane >> 4;

  __shared__ float Zs[32][268];   // 268 pad: kills l4-lane same-bank conflicts

  f32x4 acc[2][4];
#pragma unroll
  for (int m = 0; m < 2; m++)
#pragma unroll
    for (int n = 0; n < 4; n++) acc[m][n] = (f32x4){0.f, 0.f, 0.f, 0.f};

  const unsigned short* Bh = WcTph + (size_t)c * 65536;
  const unsigned short* Bl = WcTpl + (size_t)c * 65536;

  for (int kk8 = 0; kk8 < 8; kk8++) {
    s16x8 ah[2], al[2], bh[4], bl[4];
#pragma unroll
    for (int m = 0; m < 2; m++) {
      const int off = packOff(bx * 2 + m, kk8, l4, l15, 0);
      ah[m] = *reinterpret_cast<const s16x8*>(visPh + off);
      al[m] = *reinterpret_cast<const s16x8*>(visPl + off);
    }
#pragma unroll
    for (int n = 0; n < 4; n++) {
      const int off = packOff(wvi * 4 + n, kk8, l4, l15, 0);
      bh[n] = *reinterpret_cast<const s16x8*>(Bh + off);
      bl[n] = *reinterpret_cast<const s16x8*>(Bl + off);
    }
#pragma unroll
    for (int m = 0; m < 2; m++)
#pragma unroll
      for (int n = 0; n < 4; n++) {
        acc[m][n] = MFMA16(ah[m], bh[n], acc[m][n], 0, 0, 0);
        acc[m][n] = MFMA16(ah[m], bl[n], acc[m][n], 0, 0, 0);
        acc[m][n] = MFMA16(al[m], bh[n], acc[m][n], 0, 0, 0);
      }
  }

#pragma unroll
  for (int m = 0; m < 2; m++)
#pragma unroll
    for (int n = 0; n < 4; n++) {
      const int col = wvi * 64 + n * 16 + l15;
      const float bcv = bc[c * Hq + col];
#pragma unroll
      for (int r = 0; r < 4; r++)
        Zs[m * 16 + l4 * 4 + r][col] = acc[m][n][r] + bcv;
    }
  __syncthreads();

  // ---- LN + relu + add x -> linear hi/lo write; u/vv dot products ----
  const int row = tid >> 3, sub = tid & 7;
  const int grow = b0 + row;
  const size_t xrow = ((size_t)grow * Cq + c) * Hq;
  float zz[32];
  float sum = 0.f, sumsq = 0.f;
#pragma unroll
  for (int kq = 0; kq < 8; kq++) {
    const float4 z = *reinterpret_cast<const float4*>(&Zs[row][sub * 4 + kq * 32]);
    zz[4 * kq + 0] = z.x; zz[4 * kq + 1] = z.y;
    zz[4 * kq + 2] = z.z; zz[4 * kq + 3] = z.w;
    sum += z.x + z.y + z.z + z.w;
    sumsq += z.x * z.x + z.y * z.y + z.z * z.z + z.w * z.w;
  }
#pragma unroll
  for (int msk = 4; msk >= 1; msk >>= 1) {
    sum += __shfl_xor(sum, msk);
    sumsq += __shfl_xor(sumsq, msk);
  }
  const float mean = sum * (1.0f / Hq);
  const float var = sumsq * (1.0f / Hq) - mean * mean;
  const float inv = rsqrtf(var + EPS);

  float pu = 0.f, pv = 0.f;
#pragma unroll
  for (int kq = 0; kq < 8; kq++) {
    const int col = sub * 4 + kq * 32;
    const float4 xv = *reinterpret_cast<const float4*>(&x[xrow + col]);
    const float xr[4] = {xv.x, xv.y, xv.z, xv.w};
    s16x4 hh, ll;
#pragma unroll
    for (int e = 0; e < 4; e++) {
      float tt = (zz[4 * kq + e] - mean) * inv * gc[c * Hq + col + e] + bec[c * Hq + col + e];
      tt = fmaxf(tt, 0.f);
      const float xp = xr[e] + tt;
      const unsigned short hb2 = f2bf(xp);
      hh[e] = (short)hb2;
      ll[e] = (short)f2bf(xp - bfu(hb2));
      pu = fmaf(xp, w1[col + e], pu);
      pv = fmaf(xp, w2[col + e], pv);
    }
    *reinterpret_cast<s16x4*>(Xgh + xrow + col) = hh;   // linear, coalesced
    *reinterpret_cast<s16x4*>(Xgl + xrow + col) = ll;
  }
#pragma unroll
  for (int msk = 4; msk >= 1; msk >>= 1) {
    pu += __shfl_xor(pu, msk);
    pv += __shfl_xor(pv, msk);
  }
  if (sub == 0) {
    u[(size_t)grow * Cq + c] = pu;
    vv[(size_t)grow * Cq + c] = pv;
  }
}

// ---------------------------------------------------------------------------
// GEMM2 (repack hub): per block 32 linear X' rows -> LDS, then
//  (1) XM = X'@M (split-3) -> LDS packed stage -> coalesced packed write
//  (2) packed X' written IN-PLACE over the linear X' bytes (aliased Xh/Xl,
//      no __restrict__ on them)
//  (3) V = X'@Wv + bv (split-2) -> LDS transpose -> Vt[b][h][c] (32B runs)
// ---------------------------------------------------------------------------
__global__ __launch_bounds__(256) void k_gemm2p(
    unsigned short* Xh, unsigned short* Xl,       // aliased on purpose
    const unsigned short* __restrict__ MTph, const unsigned short* __restrict__ MTpl,
    const unsigned short* __restrict__ WvTp, const float* __restrict__ bv,
    unsigned short* __restrict__ XMh, unsigned short* __restrict__ XMl,
    unsigned short* __restrict__ Vt) {
  __shared__ __attribute__((aligned(16))) unsigned short Xsh[32 * 264];
  __shared__ __attribute__((aligned(16))) unsigned short Xsl[32 * 264];
  __shared__ __attribute__((aligned(16))) unsigned short XMsh[8192];
  __shared__ __attribute__((aligned(16))) unsigned short XMsl[8192];
  __shared__ __attribute__((aligned(16))) unsigned short Vst[256 * 24];

  const int blk = blockIdx.x;
  const int r0 = blk * 32;
  const int tid = threadIdx.x;
  const int wvi = tid >> 6, lane = tid & 63;
  const int l15 = lane & 15, l4 = lane >> 4;

  // ---- stage 32 linear rows (hi+lo) into LDS, 264-padded ----
#pragma unroll
  for (int it = 0; it < 4; it++) {
    const int ch = it * 256 + tid;            // 1024 chunks of 16B
    const int rr = ch >> 5, cc = ch & 31;
    const size_t gsrc = (size_t)(r0 + rr) * Hq + cc * 8;
    *reinterpret_cast<s16x8*>(&Xsh[rr * 264 + cc * 8]) =
        *reinterpret_cast<const s16x8*>(Xh + gsrc);
    *reinterpret_cast<s16x8*>(&Xsl[rr * 264 + cc * 8]) =
        *reinterpret_cast<const s16x8*>(Xl + gsrc);
  }
  __syncthreads();

  // ---- XM = X' @ M (split-3), A from LDS, B packed global ----
  f32x4 acc[2][4];
#pragma unroll
  for (int m = 0; m < 2; m++)
#pragma unroll
    for (int n = 0; n < 4; n++) acc[m][n] = (f32x4){0.f, 0.f, 0.f, 0.f};

  for (int kk8 = 0; kk8 < 8; kk8++) {
    s16x8 ah[2], al[2], bh[4], bl[4];
#pragma unroll
    for (int m = 0; m < 2; m++) {
      const int lo = (m * 16 + l15) * 264 + kk8 * 32 + l4 * 8;
      ah[m] = *reinterpret_cast<const s16x8*>(&Xsh[lo]);
      al[m] = *reinterpret_cast<const s16x8*>(&Xsl[lo]);
    }
#pragma unroll
    for (int n = 0; n < 4; n++) {
      const int off = packOff(wvi * 4 + n, kk8, l4, l15, 0);
      bh[n] = *reinterpret_cast<const s16x8*>(MTph + off);
      bl[n] = *reinterpret_cast<const s16x8*>(MTpl + off);
    }
#pragma unroll
    for (int m = 0; m < 2; m++)
#pragma unroll
      for (int n = 0; n < 4; n++) {
        acc[m][n] = MFMA16(ah[m], bh[n], acc[m][n], 0, 0, 0);
        acc[m][n] = MFMA16(ah[m], bl[n], acc[m][n], 0, 0, 0);
        acc[m][n] = MFMA16(al[m], bh[n], acc[m][n], 0, 0, 0);
      }
  }

  // scatter into LDS packed image of the 2 tiles
#pragma unroll
  for (int m = 0; m < 2; m++)
#pragma unroll
    for (int n = 0; n < 4; n++) {
      const int col = wvi * 64 + n * 16 + l15;
      const int kk8c = col >> 5, gc = (col & 31) >> 3, ec = col & 7;
#pragma unroll
      for (int r = 0; r < 4; r++) {
        const int off = ((m * 8 + kk8c) * 4 + gc) * 128 + (l4 * 4 + r) * 8 + ec;
        const float v = acc[m][n][r];
        const unsigned short hb = f2bf(v);
        XMsh[off] = hb;
        XMsl[off] = f2bf(v - bfu(hb));
      }
    }
  __syncthreads();

  // coalesced flush: XM packed + X' packed (overwrites this block's linear X bytes)
#pragma unroll
  for (int it = 0; it < 4; it++) {
    const int ch = it * 256 + tid;            // 1024 chunks of 16B
    const size_t gdst = (size_t)blk * 8192 + ch * 8;
    *reinterpret_cast<s16x8*>(XMh + gdst) = *reinterpret_cast<const s16x8*>(&XMsh[ch * 8]);
    *reinterpret_cast<s16x8*>(XMl + gdst) = *reinterpret_cast<const s16x8*>(&XMsl[ch * 8]);
    // packed X' chunk ch -> (mm, kk, g, l15c)
    const int l15c = ch & 15, g3 = (ch >> 4) & 3, kk = (ch >> 6) & 7, mm = ch >> 9;
    const int lsrc = (mm * 16 + l15c) * 264 + kk * 32 + g3 * 8;
    *reinterpret_cast<s16x8*>(Xh + gdst) = *reinterpret_cast<const s16x8*>(&Xsh[lsrc]);
    *reinterpret_cast<s16x8*>(Xl + gdst) = *reinterpret_cast<const s16x8*>(&Xsl[lsrc]);
  }

  // ---- V = X' @ Wv + bv (split-2), per tile; LDS transpose -> Vt ----
  for (int m = 0; m < 2; m++) {
    f32x4 vac[4];
#pragma unroll
    for (int n = 0; n < 4; n++) vac[n] = (f32x4){0.f, 0.f, 0.f, 0.f};
    for (int kk8 = 0; kk8 < 8; kk8++) {
      const int lo = (m * 16 + l15) * 264 + kk8 * 32 + l4 * 8;
      const s16x8 ah = *reinterpret_cast<const s16x8*>(&Xsh[lo]);
      const s16x8 al = *reinterpret_cast<const s16x8*>(&Xsl[lo]);
#pragma unroll
      for (int n = 0; n < 4; n++) {
        const s16x8 bh = *reinterpret_cast<const s16x8*>(
            WvTp + packOff(wvi * 4 + n, kk8, l4, l15, 0));
        vac[n] = MFMA16(ah, bh, vac[n], 0, 0, 0);
        vac[n] = MFMA16(al, bh, vac[n], 0, 0, 0);
      }
    }
#pragma unroll
    for (int n = 0; n < 4; n++) {
      const int col = (wvi * 4 + n) * 16 + l15;
      const float bvv = bv[col];
#pragma unroll
      for (int r = 0; r < 4; r++)
        Vst[col * 24 + l4 * 4 + r] = f2bf(vac[n][r] + bvv);
    }
    __syncthreads();
    {
      const int gt = blk * 2 + m;
      const int bb = gt / 5, ct = gt - bb * 5;
      const unsigned short* src = &Vst[tid * 24];
      const s16x8 va = *reinterpret_cast<const s16x8*>(src);
      const s16x8 vb2 = *reinterpret_cast<const s16x8*>(src + 8);
      const size_t ga = ((size_t)bb * Hq + tid) * Cq + ct * 16;
      *reinterpret_cast<s16x8*>(Vt + ga) = va;
      *reinterpret_cast<s16x8*>(Vt + ga + 8) = vb2;
    }
    __syncthreads();
  }
}

// ---------------------------------------------------------------------------
// Attention v9 (hybrid): attn7's 2-deep pipelined + LDS-deduped QK front,
// attn5's measured tail (softmax, P, PV from global Vt[b][h][c], Olds,
// out-proj, direct store). QK dbuf (40.96KB) unions with Olds (42.24KB).
// ---------------------------------------------------------------------------
__global__ __launch_bounds__(320) void k_attn9(
    const unsigned short* __restrict__ XPh, const unsigned short* __restrict__ XPl,
    const unsigned short* __restrict__ XMh, const unsigned short* __restrict__ XMl,
    const unsigned short* __restrict__ Vt, const int* __restrict__ labels,
    const float* __restrict__ u, const float* __restrict__ vv,
    const float* __restrict__ cqk, const unsigned short* __restrict__ WoTp,
    const float* __restrict__ bo, float* __restrict__ out) {
  __shared__ __attribute__((aligned(16))) unsigned short areaA[21120]; // 42240B: QK dbuf then Olds[80][264]
  __shared__ __attribute__((aligned(16))) unsigned short Pl_[80][104]; // 16640 B
  __shared__ float us[80], vvs[80], lms[80];

  const int b = blockIdx.x, t = threadIdx.x;
  const int w = t >> 6, lane = t & 63;
  const int l15 = lane & 15, g = lane >> 4;
  const int tb = b * 5;

  if (t < 80) {
    us[t] = u[b * Cq + t];
    vvs[t] = vv[b * Cq + t];
    lms[t] = (float)labels[b * Cq + t] * 0.8f + 0.2f;
  }

  // chunk j: 0-4 XPh tile j | 5-9 XPl | 10-14 XMh | 15-19 XMl
#define LOADSLICE(dst, KK)                                                      \
  {                                                                             \
    _Pragma("unroll")                                                           \
    for (int q = 0; q < 4; q++) {                                               \
      const int j = 4 * w + q;                                                  \
      const unsigned short* base = (j < 5) ? XPh : (j < 10) ? XPl               \
                                   : (j < 15) ? XMh : XMl;                      \
      const int tile = tb + (j % 5);                                            \
      dst[q] = *reinterpret_cast<const s16x8*>(                                 \
          base + (size_t)(tile * 8 + (KK)) * 512 + lane * 8);                   \
    }                                                                           \
  }
#define WRITESLICE(src, BUF)                                                    \
  {                                                                             \
    _Pragma("unroll")                                                           \
    for (int q = 0; q < 4; q++)                                                 \
      *reinterpret_cast<s16x8*>(                                                \
          &areaA[(BUF) * 10240 + (4 * w + q) * 512 + lane * 8]) = src[q];       \
  }

  f32x4 sacc[5];
#pragma unroll
  for (int mt = 0; mt < 5; mt++) sacc[mt] = (f32x4){0.f, 0.f, 0.f, 0.f};

  // prologue: slice0 -> buf0; slice1 in flight (sB)
  s16x8 sA[4], sB[4];
  LOADSLICE(sA, 0);
  LOADSLICE(sB, 1);
  WRITESLICE(sA, 0);
  __syncthreads();

#define QKSTEP(K, LD, WR)                                                       \
  {                                                                             \
    if ((K) < 6) LOADSLICE(LD, (K) + 2);                                        \
    const unsigned short* B0 = &areaA[((K) & 1) * 10240];                       \
    const s16x8 bh = *reinterpret_cast<const s16x8*>(B0 + (10 + w) * 512 + lane * 8);  \
    const s16x8 bl = *reinterpret_cast<const s16x8*>(B0 + (15 + w) * 512 + lane * 8);  \
    _Pragma("unroll")                                                           \
    for (int mt = 0; mt < 5; mt++) {                                            \
      const s16x8 ah = *reinterpret_cast<const s16x8*>(B0 + mt * 512 + lane * 8);      \
      const s16x8 al = *reinterpret_cast<const s16x8*>(B0 + (5 + mt) * 512 + lane * 8);\
      sacc[mt] = MFMA16(ah, bh, sacc[mt], 0, 0, 0);                             \
      sacc[mt] = MFMA16(ah, bl, sacc[mt], 0, 0, 0);                             \
      sacc[mt] = MFMA16(al, bh, sacc[mt], 0, 0, 0);                             \
    }                                                                           \
    if ((K) < 7) WRITESLICE(WR, ((K) + 1) & 1);                                 \
    __syncthreads();                                                            \
  }

  QKSTEP(0, sA, sB)
  QKSTEP(1, sB, sA)
  QKSTEP(2, sA, sB)
  QKSTEP(3, sB, sA)
  QKSTEP(4, sA, sB)
  QKSTEP(5, sB, sA)
  QKSTEP(6, sA, sB)
  QKSTEP(7, sB, sA)
#undef QKSTEP
#undef LOADSLICE
#undef WRITESLICE

  // ---- mask + softmax over j (attn5 tail) ----
  const int i = 16 * w + l15;
  const float ui = us[i];
  const float cq = *cqk;
  float p[5][4];
  float mx = -1e30f;
#pragma unroll
  for (int mt = 0; mt < 5; mt++)
#pragma unroll
    for (int r = 0; r < 4; r++) {
      const int j = 16 * mt + 4 * g + r;
      float sc = (sacc[mt][r] + ui + vvs[j] + cq) * SCALE;
      sc = (sc > THR) ? sc : 0.0f;
      sc *= lms[j];
      p[mt][r] = sc;
      mx = fmaxf(mx, sc);
    }
  mx = fmaxf(mx, __shfl_xor(mx, 16));
  mx = fmaxf(mx, __shfl_xor(mx, 32));
  float sum = 0.f;
#pragma unroll
  for (int mt = 0; mt < 5; mt++)
#pragma unroll
    for (int r = 0; r < 4; r++) {
      const float e = __expf(p[mt][r] - mx);
      p[mt][r] = e;
      sum += e;
    }
  sum += __shfl_xor(sum, 16);
  sum += __shfl_xor(sum, 32);
  const float inv = 1.0f / sum;

#pragma unroll
  for (int mt = 0; mt < 5; mt++) {
    uint2 pk;
    pk.x = (unsigned)f2bf(p[mt][0] * inv) | ((unsigned)f2bf(p[mt][1] * inv) << 16);
    pk.y = (unsigned)f2bf(p[mt][2] * inv) | ((unsigned)f2bf(p[mt][3] * inv) << 16);
    *reinterpret_cast<uint2*>(reinterpret_cast<char*>(&Pl_[i][0]) + 32 * mt + 8 * g) = pk;
  }
  if (t < 160) {   // zero pad j in [80,96)
    const uint4 z = {0u, 0u, 0u, 0u};
    *reinterpret_cast<uint4*>(reinterpret_cast<char*>(&Pl_[t >> 1][0]) + 160 + 16 * (t & 1)) = z;
  }
  __syncthreads();

  s16x8 pa[3];
#pragma unroll
  for (int ks = 0; ks < 3; ks++)
    pa[ks] = *reinterpret_cast<const s16x8*>(
        reinterpret_cast<const char*>(&Pl_[i][0]) + 64 * ks + 16 * g);

  f32x4 oacc[16];
#pragma unroll
  for (int n = 0; n < 16; n++) oacc[n] = (f32x4){0.f, 0.f, 0.f, 0.f};

  const size_t vbase = (size_t)b * Hq * Cq;
#pragma unroll 4
  for (int n = 0; n < 16; n++) {
    const size_t hrow = vbase + (size_t)(16 * n + l15) * Cq + 8 * g;
#pragma unroll
    for (int ks = 0; ks < 3; ks++) {
      const s16x8 vb = *reinterpret_cast<const s16x8*>(Vt + hrow + 32 * ks);
      oacc[n] = MFMA16(pa[ks], vb, oacc[n], 0, 0, 0);
    }
  }

  // ---- O bf16 -> areaA as Olds[80][264] (QK dbuf dead; wave-local rows) ----
  unsigned short (*Olds)[264] = reinterpret_cast<unsigned short (*)[264]>(areaA);
#pragma unroll
  for (int n = 0; n < 16; n++)
#pragma unroll
    for (int r = 0; r < 4; r++)
      Olds[16 * w + 4 * g + r][16 * n + l15] = f2bf(oacc[n][r]);
  // wave-local rows only: no barrier needed

  f32x4 acc2[16];
#pragma unroll
  for (int n = 0; n < 16; n++) acc2[n] = (f32x4){0.f, 0.f, 0.f, 0.f};

  for (int ks = 0; ks < 8; ks++) {
    const s16x8 af = *reinterpret_cast<const s16x8*>(
        reinterpret_cast<const char*>(&Olds[16 * w + l15][0]) + 64 * ks + 16 * g);
#pragma unroll
    for (int n = 0; n < 16; n++) {
      const s16x8 bf = *reinterpret_cast<const s16x8*>(WoTp + packOff(n, ks, g, l15, 0));
      acc2[n] = MFMA16(af, bf, acc2[n], 0, 0, 0);
    }
  }

#pragma unroll
  for (int n = 0; n < 16; n++) {
    const float bov = bo[16 * n + l15];
#pragma unroll
    for (int r = 0; r < 4; r++)
      out[((size_t)b * Cq + 16 * w + 4 * g + r) * Hq + 16 * n + l15] =
          acc2[n][r] + bov;
  }
}

// ---------------------------------------------------------------------------
extern "C" void kernel_launch(void* const* d_in, const int* in_sizes, int n_in,
                              void* d_out, int out_size, void* d_ws, size_t ws_size,
                              hipStream_t stream) {
  const float* x   = (const float*)d_in[0];
  const float* vf  = (const float*)d_in[1];
  const int*   lab = (const int*)d_in[2];
  const float* Wp  = (const float*)d_in[3];
  const float* bp  = (const float*)d_in[4];
  const float* gp  = (const float*)d_in[5];
  const float* bep = (const float*)d_in[6];
  const float* Wc  = (const float*)d_in[7];
  const float* bc  = (const float*)d_in[8];
  const float* gc  = (const float*)d_in[9];
  const float* bec = (const float*)d_in[10];
  const float* Wq  = (const float*)d_in[11];
  const float* bq_ = (const float*)d_in[12];
  const float* Wk  = (const float*)d_in[13];
  const float* bk_ = (const float*)d_in[14];
  const float* Wv  = (const float*)d_in[15];
  const float* bv_ = (const float*)d_in[16];
  const float* Wo  = (const float*)d_in[17];
  const float* bo_ = (const float*)d_in[18];
  float* out = (float*)d_out;
  (void)ws_size; (void)in_sizes; (void)n_in; (void)out_size;

  char* W = (char*)d_ws;
  unsigned short* Xh    = (unsigned short*)(W + 0);           // 20,971,520 (linear X', repacked in-place)
  unsigned short* Xl    = (unsigned short*)(W + 20971520);    // 20,971,520
  unsigned short* WcTph = (unsigned short*)(W + 41943040);    // 10,485,760
  unsigned short* WcTpl = (unsigned short*)(W + 52428800);    // 10,485,760
  unsigned short* XMh   = (unsigned short*)(W + 41943040);    // 20,971,520 (aliases WcT, dead after gemm1f)
  unsigned short* XMl   = (unsigned short*)(W + 62914560);    // 20,971,520
  unsigned short* Vt    = (unsigned short*)(W + 83886080);    // 20,971,520  [b][h][c]
  unsigned short* visPh = (unsigned short*)(W + 104857600);   // 262,144
  unsigned short* visPl = (unsigned short*)(W + 105119744);   // 262,144
  unsigned short* MTph  = (unsigned short*)(W + 105381888);   // 131,072
  unsigned short* MTpl  = (unsigned short*)(W + 105512960);   // 131,072
  unsigned short* WvTp  = (unsigned short*)(W + 105644032);   // 131,072
  unsigned short* WoTp  = (unsigned short*)(W + 105775104);   // 131,072
  float* w1  = (float*)(W + 105906176);                       // 1,024
  float* w2  = (float*)(W + 105907200);                       // 1,024
  float* cqk = (float*)(W + 105908224);                       // 256
  float* u   = (float*)(W + 105908480);                       // 163,840
  float* vvv = (float*)(W + 106072320);                       // 163,840 -> end 106,236,160

  k_setup<<<1792, 256, 0, stream>>>(vf, Wp, bp, gp, bep, visPh, visPl,
                                    Wq, Wk, bq_, bk_, MTph, MTpl, w1, w2, cqk,
                                    Wc, Wv, Wo, WcTph, WcTpl, WvTp, WoTp);
  k_gemm1f<<<1280, 256, 0, stream>>>(visPh, visPl, WcTph, WcTpl, x, bc, gc, bec,
                                     w1, w2, Xh, Xl, u, vvv);
  k_gemm2p<<<1280, 256, 0, stream>>>(Xh, Xl, MTph, MTpl, WvTp, bv_,
                                     XMh, XMl, Vt);
  k_attn9<<<Bq, 320, 0, stream>>>(Xh, Xl, XMh, XMl, Vt, lab, u, vvv, cqk,
                                  WoTp, bo_, out);
}